// Round 8
// baseline (1910.504 us; speedup 1.0000x reference)
//
#include <hip/hip_runtime.h>

// Problem constants
#define BB    512
#define TT    300
#define DD    128
#define HH    256
#define GG    1024      // 4*H
#define DNS   256
#define NC    14
#define KDIM  76800     // T*H

typedef _Float16 f16;
typedef _Float16 f16x8 __attribute__((ext_vector_type(8)));
typedef float    f32x4 __attribute__((ext_vector_type(4)));

__device__ __forceinline__ float sigf(float x){ return 1.0f / (1.0f + __expf(-x)); }
__device__ __forceinline__ float tanhfast(float x){ return 2.0f / (1.0f + __expf(-2.0f*x)) - 1.0f; }

// ---------------- K1: embedding gather, fp32 -> fp16 x[B][T][D] ----------------
__global__ void k_gather(const int* __restrict__ idx, const float* __restrict__ emb,
                         f16* __restrict__ xbuf)
{
    int gid = blockIdx.x * 256 + threadIdx.x;       // one 4-dim chunk
    if (gid >= BB*TT*DD/4) return;
    int bt = gid >> 5;                              // 32 chunks per 128-dim row
    int c4 = gid & 31;
    int v  = idx[bt];
    const float4 e = *(const float4*)(emb + (size_t)v*DD + c4*4);
    union { f16 h[4]; uint2 u; } o;
    o.h[0]=(f16)e.x; o.h[1]=(f16)e.y; o.h[2]=(f16)e.z; o.h[3]=(f16)e.w;
    *(uint2*)(xbuf + (size_t)bt*DD + c4*4) = o.u;
}

// ---------------- K2: persistent LSTM recurrence ----------------
// Round-8: pair cliques + 2-phase interleave. 128 blocks = 64 batch-slices
// (8 rows, as TWO independent 4-row cliques A/B) x 2 slots (128 dims).
// W slice (512 gate rows x 384 K) register-resident: 48 f16x8 = 192 VGPR/lane.
// Per phase a block exchanges with ONE peer (blockIdx ^ 64; same XCD under
// round-robin dispatch - perf heuristic only). Tag-in-word ((t<<16)|f16) in
// depth-2 ping-pong hpp[t&1][b][dim]; each thread publishes 1 word and polls
// 1 word. Phases alternate A,B: each publish gets a full phase of slack
// before its consumer needs it, hiding the MALL write->visible latency;
// phase-end OPTIMISTIC PREFETCH of the next phase's foreign word hides the
// read RTT (tag-checked at phase start, re-poll fallback).
// Own-slice h stays in a register between phases (Ast reused by both).
// Depth-2 ping-pong race-free: publish(t+2) causally requires peer consumed t.
__global__ __launch_bounds__(512) void k_lstm(
    const f16* __restrict__ xbuf, f16* __restrict__ hs,
    const float* __restrict__ Wih, const float* __restrict__ Whh,
    const float* __restrict__ bih, const float* __restrict__ bhh,
    unsigned int* hpp)
{
    __shared__ f16   Ast[16*392];    // 16 rows (4 real) x (256 h | 128 x | 8 pad)
    __shared__ float gbuf[4*520];    // gates [m][q], q = 4*d+ty, pad 520
    __shared__ float biasS[512];

    const int tid  = threadIdx.x;
    const int bsI  = blockIdx.x & 63;               // batch-slice (8 rows)
    const int sI   = blockIdx.x >> 6;               // slot 0/1 (128 dims)
    const int r0   = bsI*8;
    const int j0   = sI*128, fj0 = 128 - j0;        // own / foreign dim base
    const int wv   = tid >> 6, lane = tid & 63;
    const int q16  = lane & 15, quad = lane >> 4;

    // ---- resident W fragments: wave wv owns n-tiles wv*4 .. wv*4+3 ----
    f16x8 bf[4][12];
    #pragma unroll
    for (int nt = 0; nt < 4; ++nt) {
        const int ql   = (wv*4 + nt)*16 + q16;      // local gate 0..511
        const int dl   = ql >> 2, ty = ql & 3;      // q = 4*d + ty
        const int Grow = ty*HH + j0 + dl;           // global gate row
        const float* wh = Whh + (size_t)Grow*HH;
        #pragma unroll
        for (int kk = 0; kk < 8; ++kk) {
            const float* p = wh + kk*32 + quad*8;
            float4 f0 = *(const float4*)p, f1 = *(const float4*)(p+4);
            f16x8 b;
            b[0]=(f16)f0.x; b[1]=(f16)f0.y; b[2]=(f16)f0.z; b[3]=(f16)f0.w;
            b[4]=(f16)f1.x; b[5]=(f16)f1.y; b[6]=(f16)f1.z; b[7]=(f16)f1.w;
            bf[nt][kk] = b;
        }
        const float* wi = Wih + (size_t)Grow*DD;
        #pragma unroll
        for (int kk = 0; kk < 4; ++kk) {
            const float* p = wi + kk*32 + quad*8;
            float4 f0 = *(const float4*)p, f1 = *(const float4*)(p+4);
            f16x8 b;
            b[0]=(f16)f0.x; b[1]=(f16)f0.y; b[2]=(f16)f0.z; b[3]=(f16)f0.w;
            b[4]=(f16)f1.x; b[5]=(f16)f1.y; b[6]=(f16)f1.z; b[7]=(f16)f1.w;
            bf[nt][8+kk] = b;
        }
    }
    {   // biases for the 512 local gates
        const int dl = tid >> 2, ty = tid & 3;
        biasS[tid] = bih[ty*HH + j0 + dl] + bhh[ty*HH + j0 + dl];
    }
    // zero all of Ast once (rows 4..15 are MFMA padding, never written again)
    for (int i = tid; i < 16*392*2/8; i += 512)
        ((unsigned long long*)Ast)[i] = 0ull;
    __syncthreads();

    float          cst[2]  = {0.f, 0.f};            // cell state per phase
    unsigned short hReg[2] = {0, 0};                // own h(t-1) bits per phase
    const int prow = tid >> 7;                      // local row 0..3
    const int d    = tid & 127;                     // local dim 0..127
    unsigned int pref = 0;                          // prefetched foreign word

    for (int t = 0; t < TT; ++t) {
        #pragma unroll
        for (int p = 0; p < 2; ++p) {
            const int rb = r0 + p*4;
            // ---- stage x_t: 4 rows x 16 16B-chunks (cached loads) ----
            if (tid < 64) {
                int row = tid >> 4, ch = tid & 15;
                *(uint4*)(Ast + (size_t)row*392 + 256 + ch*8) =
                    *(const uint4*)(xbuf + ((size_t)(rb+row)*TT + t)*DD + ch*8);
            }
            if (t > 0) {
                // own h(t-1) from register
                union { unsigned short us; f16 hf; } uo; uo.us = hReg[p];
                Ast[prow*392 + j0 + d] = uo.hf;
                // foreign h(t-1): prefetched word, tag-checked; re-poll fallback
                const unsigned tgt = (unsigned)(t-1);
                unsigned w = pref;
                unsigned int* ap = hpp + (size_t)((t-1)&1)*BB*HH
                                       + (size_t)(rb+prow)*HH + fj0 + d;
                while ((w >> 16) != tgt) {
                    __builtin_amdgcn_s_sleep(1);
                    w = __hip_atomic_load(ap, __ATOMIC_RELAXED,
                                          __HIP_MEMORY_SCOPE_AGENT);
                }
                union { unsigned short us; f16 hf; } uf; uf.us = (unsigned short)w;
                Ast[prow*392 + fj0 + d] = uf.hf;
            } else {
                Ast[prow*392 + j0 + d]  = (f16)0.f;
                Ast[prow*392 + fj0 + d] = (f16)0.f;
            }
            __syncthreads();   // syncA: Ast complete

            // ---- gates[m][q] = sum_k A[m,k] * W[q,k]; 4 n-tiles/wave ----
            f32x4 acc[4];
            #pragma unroll
            for (int nt = 0; nt < 4; ++nt) acc[nt] = (f32x4){0.f,0.f,0.f,0.f};
            const f16* arow = Ast + q16*392 + quad*8;
            #pragma unroll
            for (int kk = 0; kk < 12; ++kk) {
                f16x8 a = *(const f16x8*)(arow + kk*32);
                #pragma unroll
                for (int nt = 0; nt < 4; ++nt)
                    acc[nt] = __builtin_amdgcn_mfma_f32_16x16x32_f16(a, bf[nt][kk],
                                                                     acc[nt], 0, 0, 0);
            }
            // D layout: col=q16 -> q within tile, row=quad*4+r -> m (rows 0..3 real)
            if (quad == 0) {
                #pragma unroll
                for (int nt = 0; nt < 4; ++nt)
                    #pragma unroll
                    for (int r = 0; r < 4; ++r)
                        gbuf[r*520 + (wv*4+nt)*16 + q16] = acc[nt][r];
            }
            __syncthreads();   // syncB: gates ready (all Ast reads done)

            // ---- elementwise LSTM cell: (row prow, dim d) ----
            float h;
            {
                const float4 g  = *(const float4*)(gbuf  + prow*520 + d*4);
                const float4 bs = *(const float4*)(biasS + d*4);
                float gi = g.x + bs.x, gf = g.y + bs.y;
                float gg = g.z + bs.z, go = g.w + bs.w;
                float iv = sigf(gi), fv = sigf(gf), gv = tanhfast(gg), ov = sigf(go);
                float c = fv*cst[p] + iv*gv;
                cst[p] = c;
                h = ov * tanhfast(c);
            }
            union { unsigned short us; f16 hf; } cv; cv.hf = (f16)h;
            hReg[p] = cv.us;
            // publish tagged word (validity travels with data)
            __hip_atomic_store(hpp + (size_t)(t&1)*BB*HH + (size_t)(rb+prow)*HH + j0 + d,
                               ((unsigned)t << 16) | cv.us,
                               __ATOMIC_RELAXED, __HIP_MEMORY_SCOPE_AGENT);
            // hs for the dense layer (off the critical path)
            hs[((size_t)(rb+prow)*TT + t)*HH + j0 + d] = cv.hf;
            // ---- optimistic prefetch of NEXT phase's foreign word ----
            {
                const int tn = (p == 0) ? t : t + 1;     // next phase = (1-p, tn)
                unsigned int* apn = hpp + (size_t)((tn-1)&1)*BB*HH
                                        + (size_t)(r0 + (1-p)*4 + prow)*HH + fj0 + d;
                pref = __hip_atomic_load(apn, __ATOMIC_RELAXED,
                                         __HIP_MEMORY_SCOPE_AGENT);
            }
        }
    }
}

// ---------------- K3: dense GEMM, split-K -> partials ----------------
// A = hs (fp16), B = W3 (fp32, converted to fp16 during LDS staging).
__global__ __launch_bounds__(256) void k_dense(
    const f16* __restrict__ hs, const float* __restrict__ W3, float* __restrict__ part)
{
    __shared__ f16 Ap[128*40];
    __shared__ f16 Bp[128*40];
    const int tid = threadIdx.x;
    const int kb = blockIdx.x & 31, tn = (blockIdx.x >> 5) & 1, tm = blockIdx.x >> 6;
    const int m0 = tm*128, n0 = tn*128;
    const long k0 = (long)kb * 2400;
    const int wv = tid >> 6, lane = tid & 63, q16 = lane & 15, quad = lane >> 4;

    f32x4 acc[2][8];
    #pragma unroll
    for (int a = 0; a < 2; ++a)
        #pragma unroll
        for (int b = 0; b < 8; ++b) acc[a][b] = (f32x4){0.f,0.f,0.f,0.f};

    for (int ks = 0; ks < 75; ++ks) {
        const long kbase = k0 + ks*32;
        #pragma unroll
        for (int rep = 0; rep < 4; ++rep) {
            int cid = tid + rep*256;                 // 1024 chunks: 512 A + 512 B
            int rrow = (cid & 511) >> 2;
            int c4   = cid & 3;
            if (cid < 512) {
                const f16* src = hs + (size_t)(m0+rrow)*KDIM + kbase + c4*8;
                *(uint4*)(Ap + rrow*40 + c4*8) = *(const uint4*)src;
            } else {
                const float* src = W3 + (size_t)(n0+rrow)*KDIM + kbase + c4*8;
                float4 f0 = *(const float4*)src, f1 = *(const float4*)(src+4);
                union { f16 h[8]; uint4 u; } o;
                o.h[0]=(f16)f0.x; o.h[1]=(f16)f0.y; o.h[2]=(f16)f0.z; o.h[3]=(f16)f0.w;
                o.h[4]=(f16)f1.x; o.h[5]=(f16)f1.y; o.h[6]=(f16)f1.z; o.h[7]=(f16)f1.w;
                *(uint4*)(Bp + rrow*40 + c4*8) = o.u;
            }
        }
        __syncthreads();

        f16x8 a0 = *(const f16x8*)(Ap + ((wv*2+0)*16 + q16)*40 + quad*8);
        f16x8 a1 = *(const f16x8*)(Ap + ((wv*2+1)*16 + q16)*40 + quad*8);
        #pragma unroll
        for (int ns = 0; ns < 8; ++ns) {
            f16x8 b = *(const f16x8*)(Bp + (ns*16 + q16)*40 + quad*8);
            acc[0][ns] = __builtin_amdgcn_mfma_f32_16x16x32_f16(a0, b, acc[0][ns], 0,0,0);
            acc[1][ns] = __builtin_amdgcn_mfma_f32_16x16x32_f16(a1, b, acc[1][ns], 0,0,0);
        }
        __syncthreads();
    }
    #pragma unroll
    for (int ms = 0; ms < 2; ++ms)
        #pragma unroll
        for (int ns = 0; ns < 8; ++ns)
            #pragma unroll
            for (int r = 0; r < 4; ++r) {
                int m = m0 + (wv*2+ms)*16 + quad*4 + r;
                int n = n0 + ns*16 + q16;
                part[(size_t)kb*BB*DNS + (size_t)m*DNS + n] = acc[ms][ns][r];
            }
}

// ---------------- K4: reduce split-K partials + bias + relu ----------------
__global__ void k_reduce(const float* __restrict__ part, const float* __restrict__ b3,
                         float* __restrict__ dens)
{
    int g = blockIdx.x * 256 + threadIdx.x;
    if (g >= BB*DNS) return;
    int n = g & 255;
    float s = b3[n];
    #pragma unroll
    for (int kb = 0; kb < 32; ++kb) s += part[(size_t)kb*BB*DNS + g];
    dens[g] = fmaxf(s, 0.0f);
}

// ---------------- K5: final 256->14 + softmax ----------------
__global__ __launch_bounds__(64) void k_final(
    const float* __restrict__ dens, const float* __restrict__ W4,
    const float* __restrict__ b4, float* __restrict__ out)
{
    const int b = blockIdx.x, lane = threadIdx.x;
    const float4 dv = *(const float4*)(dens + (size_t)b*DNS + lane*4);
    float lg[NC];
    #pragma unroll
    for (int cc = 0; cc < NC; ++cc) {
        const float4 w = *(const float4*)(W4 + (size_t)cc*DNS + lane*4);
        float v = dv.x*w.x + dv.y*w.y + dv.z*w.z + dv.w*w.w;
        #pragma unroll
        for (int off = 32; off; off >>= 1) v += __shfl_xor(v, off, 64);
        lg[cc] = v + b4[cc];
    }
    if (lane == 0) {
        float m = lg[0];
        #pragma unroll
        for (int cc = 1; cc < NC; ++cc) m = fmaxf(m, lg[cc]);
        float e[NC], s = 0.f;
        #pragma unroll
        for (int cc = 0; cc < NC; ++cc) { e[cc] = __expf(lg[cc]-m); s += e[cc]; }
        const float inv = 1.0f/s;
        #pragma unroll
        for (int cc = 0; cc < NC; ++cc) out[(size_t)b*NC + cc] = e[cc]*inv;
    }
}

// ---------------- launch ----------------
extern "C" void kernel_launch(void* const* d_in, const int* in_sizes, int n_in,
                              void* d_out, int out_size, void* d_ws, size_t ws_size,
                              hipStream_t stream)
{
    const int*   idx = (const int*)  d_in[0];
    // d_in[1] = traj_lens: unused by the reference
    const float* emb = (const float*)d_in[2];
    const float* Wih = (const float*)d_in[3];
    const float* Whh = (const float*)d_in[4];
    const float* bih = (const float*)d_in[5];
    const float* bhh = (const float*)d_in[6];
    const float* W3  = (const float*)d_in[7];
    const float* b3  = (const float*)d_in[8];
    const float* W4  = (const float*)d_in[9];
    const float* b4  = (const float*)d_in[10];
    float* out = (float*)d_out;

    char* ws = (char*)d_ws;
    f16*   xbuf = (f16*)  (ws);                           // 39,321,600 B
    f16*   hs   = (f16*)  (ws + 39321600);                // 78,643,200 B
    float* part = (float*)(ws + 117964800);               // 16,777,216 B
    float* dens = (float*)(ws + 134742016);               //    524,288 B
    // hpp (tagged h ping-pong, 2x512x256 uint32 = 1 MB) aliases `part`:
    // used only during k_lstm; part written only afterwards by k_dense.
    // Tags self-validate against 0xAA poison -> no memset needed.
    unsigned int* hpp = (unsigned int*)part;

    k_gather<<<19200, 256, 0, stream>>>(idx, emb, xbuf);
    k_lstm  <<<128, 512, 0, stream>>>(xbuf, hs, Wih, Whh, bih, bhh, hpp);
    k_dense <<<256, 256, 0, stream>>>(hs, W3, part);
    k_reduce<<<512, 256, 0, stream>>>(part, b3, dens);
    k_final <<<BB, 64, 0, stream>>>(dens, W4, b4, out);
}